// Round 4
// baseline (311.404 us; speedup 1.0000x reference)
//
#include <hip/hip_runtime.h>
#include <math.h>

#define DDIM 4096
#define NSEG 100
#define HDIM 128
#define BROWS 4096
#define TOPK 10

// Branch-free gelu: A&S 7.1.26 erf (abs err <= 1.5e-7).
__device__ __forceinline__ float gelu_f(float x) {
    float u  = x * 0.70710678118654752440f;
    float au = fminf(fabsf(u), 3.9f);
    float t  = __builtin_amdgcn_rcpf(fmaf(0.3275911f, au, 1.0f));
    float p  = fmaf(fmaf(fmaf(fmaf(1.061405429f, t, -1.453152027f), t,
                              1.421413741f), t, -0.284496736f), t, 0.254829592f) * t;
    float e  = __expf(-au * au);
    float er = fmaf(-p, e, 1.0f);
    er = copysignf(er, u);
    return 0.5f * x * (1.0f + er);
}

// ---------- K1: seg-side GEMM partials: segp[ks][n][col], 16 k-slices of 256 ----------
// grid (25, 16), block 256
__global__ void k_seg_gemm(const float* __restrict__ seg,
                           const float* __restrict__ iw1,
                           const float* __restrict__ rw1,
                           float* __restrict__ segp) {
    __shared__ float segT[256][5];
    int ng = blockIdx.x;
    int ks = blockIdx.y * 256;
    int tid = threadIdx.x;
    #pragma unroll
    for (int j = 0; j < 4; ++j)
        segT[tid][j] = seg[(size_t)(ng * 4 + j) * DDIM + ks + tid];
    __syncthreads();

    int col = tid;
    float a0 = 0.f, a1 = 0.f, a2 = 0.f, a3 = 0.f;
    const float* w = (col < HDIM) ? (iw1 + col)
                                  : (rw1 + (size_t)DDIM * HDIM + (col - HDIM));
    #pragma unroll 8
    for (int k = 0; k < 256; ++k) {
        float wv = w[(size_t)(ks + k) * HDIM];
        a0 = fmaf(segT[k][0], wv, a0);
        a1 = fmaf(segT[k][1], wv, a1);
        a2 = fmaf(segT[k][2], wv, a2);
        a3 = fmaf(segT[k][3], wv, a3);
    }
    float* outp = segp + (size_t)blockIdx.y * (NSEG * 256) + (size_t)(ng * 4) * 256 + col;
    outp[0] = a0; outp[256] = a1; outp[512] = a2; outp[768] = a3;
}

// ---------- K2: reduce -> importance, coeff, shwT (transposed, rb1 pre-added) ----------
// grid 100, block 256
__global__ void k_seg_red(const float* __restrict__ segp,
                          const int* __restrict__ positions,
                          const float* __restrict__ ib1,
                          const float* __restrict__ iw2,
                          const float* __restrict__ ib2,
                          const float* __restrict__ rb1,
                          float* __restrict__ shwT, float* __restrict__ impA,
                          float* __restrict__ cA) {
    __shared__ float red[HDIM];
    int n = blockIdx.x, tid = threadIdx.x;
    float v = 0.f;
    #pragma unroll
    for (int s = 0; s < 16; ++s)
        v += segp[(size_t)s * (NSEG * 256) + (size_t)n * 256 + tid];
    if (tid < HDIM) {
        red[tid] = gelu_f(v + ib1[tid]) * iw2[tid];
    } else {
        int h = tid - HDIM;
        shwT[(size_t)h * NSEG + n] = v + rb1[h];   // transposed for k_score
    }
    __syncthreads();
    if (tid == 0) {
        float s = 0.f;
        for (int j = 0; j < HDIM; ++j) s += red[j];
        float imp = 1.f / (1.f + expf(-(s + ib2[0])));
        float pf = powf(0.95f, (float)NSEG - (float)positions[n] - 1.0f);
        impA[n] = imp;
        cA[n] = imp * (0.5f + 0.5f * pf);
    }
}

// ---------- K3: qh partials, fp32, 128m x 128n tile, 8x8 acc/thread, ksplit 8 ----------
// grid (32, 8), block 256 (1 block/CU). 8 stages of 16 k, register prefetch.
__global__ void k_qh(const float* __restrict__ query,
                     const float* __restrict__ rw1,
                     float* __restrict__ qhp) {
    __shared__ float As[16][132];    // [k][m], pad -> 2-way max on transposed write
    __shared__ float Bs[16][HDIM];   // [k][n]
    int tid = threadIdx.x;
    int tx = tid & 15;               // n0 = tx*8
    int ty = tid >> 4;               // m0 = ty*8
    int m0g = blockIdx.x * 128;
    int ksg = blockIdx.y * 512;

    float acc[8][8];
    #pragma unroll
    for (int i = 0; i < 8; ++i)
        #pragma unroll
        for (int j = 0; j < 8; ++j) acc[i][j] = 0.f;

    // A staging map: m = tid>>2 (+64 for second load), kq = (tid&3)*4
    int am = tid >> 2, akq = (tid & 3) * 4;
    // B staging map: bk = tid>>5 (+8 for second load), bn = (tid&31)*4
    int bk = tid >> 5, bn = (tid & 31) * 4;

    const float* aptr0 = query + (size_t)(m0g + am) * DDIM + ksg + akq;
    const float* aptr1 = query + (size_t)(m0g + 64 + am) * DDIM + ksg + akq;
    const float* bptr0 = rw1 + (size_t)(ksg + bk) * HDIM + bn;
    const float* bptr1 = rw1 + (size_t)(ksg + 8 + bk) * HDIM + bn;

    float4 a0r = *reinterpret_cast<const float4*>(aptr0);
    float4 a1r = *reinterpret_cast<const float4*>(aptr1);
    float4 b0r = *reinterpret_cast<const float4*>(bptr0);
    float4 b1r = *reinterpret_cast<const float4*>(bptr1);

    for (int s = 0; s < 32; ++s) {
        __syncthreads();
        As[akq + 0][am] = a0r.x; As[akq + 1][am] = a0r.y;
        As[akq + 2][am] = a0r.z; As[akq + 3][am] = a0r.w;
        As[akq + 0][am + 64] = a1r.x; As[akq + 1][am + 64] = a1r.y;
        As[akq + 2][am + 64] = a1r.z; As[akq + 3][am + 64] = a1r.w;
        *reinterpret_cast<float4*>(&Bs[bk][bn]) = b0r;
        *reinterpret_cast<float4*>(&Bs[bk + 8][bn]) = b1r;
        __syncthreads();
        if (s < 31) {
            int kadv = (s + 1) * 16;
            a0r = *reinterpret_cast<const float4*>(aptr0 + kadv);
            a1r = *reinterpret_cast<const float4*>(aptr1 + kadv);
            b0r = *reinterpret_cast<const float4*>(bptr0 + (size_t)kadv * HDIM);
            b1r = *reinterpret_cast<const float4*>(bptr1 + (size_t)kadv * HDIM);
        }
        #pragma unroll
        for (int k = 0; k < 16; ++k) {
            float4 av0 = *reinterpret_cast<const float4*>(&As[k][ty * 8]);
            float4 av1 = *reinterpret_cast<const float4*>(&As[k][ty * 8 + 4]);
            float4 bv0 = *reinterpret_cast<const float4*>(&Bs[k][tx * 8]);
            float4 bv1 = *reinterpret_cast<const float4*>(&Bs[k][tx * 8 + 4]);
            float am8[8] = {av0.x, av0.y, av0.z, av0.w, av1.x, av1.y, av1.z, av1.w};
            float bn8[8] = {bv0.x, bv0.y, bv0.z, bv0.w, bv1.x, bv1.y, bv1.z, bv1.w};
            #pragma unroll
            for (int i = 0; i < 8; ++i)
                #pragma unroll
                for (int j = 0; j < 8; ++j)
                    acc[i][j] = fmaf(am8[i], bn8[j], acc[i][j]);
        }
    }
    float* outp = qhp + (size_t)blockIdx.y * (BROWS * HDIM);
    #pragma unroll
    for (int i = 0; i < 8; ++i) {
        int row = m0g + ty * 8 + i;
        float4 o0 = make_float4(acc[i][0], acc[i][1], acc[i][2], acc[i][3]);
        float4 o1 = make_float4(acc[i][4], acc[i][5], acc[i][6], acc[i][7]);
        *reinterpret_cast<float4*>(&outp[(size_t)row * HDIM + tx * 8]) = o0;
        *reinterpret_cast<float4*>(&outp[(size_t)row * HDIM + tx * 8 + 4]) = o1;
    }
}

// ---------- K4: scores + top-10 + weights (no gather). grid 4096, block 256 ----------
// thread = (n = tid&127, half = tid>>7); 64 serial h-steps in registers.
__global__ void k_score(const float* __restrict__ qhp,
                        const float* __restrict__ shwT,
                        const float* __restrict__ rw2,
                        const float* __restrict__ rb2,
                        const float* __restrict__ impA,
                        const float* __restrict__ cA,
                        float* __restrict__ wvO, int* __restrict__ idxO) {
    __shared__ float2 qr[HDIM];
    __shared__ float red[256];
    __shared__ float scoresS[128], wimpS[128];
    int b = blockIdx.x, tid = threadIdx.x;

    if (tid < HDIM) {
        size_t o = (size_t)b * HDIM + tid;
        float v = 0.f;
        #pragma unroll
        for (int s = 0; s < 8; ++s) v += qhp[(size_t)s * (BROWS * HDIM) + o];
        qr[tid] = make_float2(v, rw2[tid]);
    }
    __syncthreads();

    int n = tid & 127, half = tid >> 7;
    bool valid = n < NSEG;
    float acc = 0.f;
    #pragma unroll 8
    for (int j = 0; j < 64; ++j) {
        int h = half * 64 + j;
        float2 q2 = qr[h];                       // broadcast LDS read
        float sv = valid ? shwT[(size_t)h * NSEG + n] : 0.f;  // coalesced, L1/L2-hot
        acc += gelu_f(sv + q2.x) * q2.y;
    }
    red[tid] = acc;
    __syncthreads();

    if (tid < 128) {
        float t = red[tid] + red[tid + 128];
        if (tid < NSEG) {
            float rel = 1.f / (1.f + expf(-(t + rb2[0])));
            scoresS[tid] = cA[tid] * rel;
            wimpS[tid]   = impA[tid] * rel;
        } else {
            scoresS[tid] = -1e30f;
            wimpS[tid] = 0.f;
        }
    }
    __syncthreads();

    if (tid < 64) {
        int lane = tid;
        float s1 = scoresS[lane];
        int i2 = lane + 64;
        float s2 = scoresS[i2];
        float wsum = 0.f;
        float wloc[TOPK];
        int iloc[TOPK];
        for (int k = 0; k < TOPK; ++k) {
            float s; int i;
            if (s2 > s1) { s = s2; i = i2; } else { s = s1; i = lane; }
            #pragma unroll
            for (int off = 1; off < 64; off <<= 1) {
                float os = __shfl_xor(s, off);
                int oi = __shfl_xor(i, off);
                if (os > s || (os == s && oi < i)) { s = os; i = oi; }
            }
            if (lane == 0) {
                iloc[k] = i;
                float ww = wimpS[i];
                wloc[k] = ww;
                wsum += ww;
            }
            if (i == lane) s1 = -1e30f;
            if (i == i2)   s2 = -1e30f;
        }
        if (lane == 0) {
            float dn = __builtin_amdgcn_rcpf(wsum + 1e-8f);
            // rcp approx not good enough? use exact divide for safety
            dn = (wsum + 1e-8f);
            #pragma unroll
            for (int k = 0; k < TOPK; ++k) {
                wvO[(size_t)b * 16 + k] = wloc[k] / dn;
                idxO[(size_t)b * 16 + k] = iloc[k];
            }
        }
    }
}

// ---------- K5: out = query + sum_k w_k * seg[idx_k]. grid 4096, block 256 ----------
__global__ void k_out(const float* __restrict__ query,
                      const float* __restrict__ seg,
                      const float* __restrict__ wvO,
                      const int* __restrict__ idxO,
                      float* __restrict__ out) {
    __shared__ float wS[TOPK];
    __shared__ int iS[TOPK];
    int b = blockIdx.x, tid = threadIdx.x;
    if (tid < TOPK) {
        wS[tid] = wvO[(size_t)b * 16 + tid];
        iS[tid] = idxO[(size_t)b * 16 + tid];
    }
    __syncthreads();

    float w[TOPK];
    const float* srow[TOPK];
    #pragma unroll
    for (int k = 0; k < TOPK; ++k) { w[k] = wS[k]; srow[k] = seg + (size_t)iS[k] * DDIM; }
    const float* qrow = query + (size_t)b * DDIM;
    float* orow = out + (size_t)b * DDIM;
    #pragma unroll
    for (int it = 0; it < 4; ++it) {
        int d0 = it * 1024 + tid * 4;
        float4 q4 = *reinterpret_cast<const float4*>(qrow + d0);
        #pragma unroll
        for (int k = 0; k < TOPK; ++k) {
            float4 s4 = *reinterpret_cast<const float4*>(srow[k] + d0);
            q4.x = fmaf(w[k], s4.x, q4.x); q4.y = fmaf(w[k], s4.y, q4.y);
            q4.z = fmaf(w[k], s4.z, q4.z); q4.w = fmaf(w[k], s4.w, q4.w);
        }
        *reinterpret_cast<float4*>(orow + d0) = q4;
    }
}

extern "C" void kernel_launch(void* const* d_in, const int* in_sizes, int n_in,
                              void* d_out, int out_size, void* d_ws, size_t ws_size,
                              hipStream_t stream) {
    const float* query = (const float*)d_in[0];
    const float* seg   = (const float*)d_in[1];
    const int*   pos   = (const int*)d_in[2];
    const float* iw1   = (const float*)d_in[3];
    const float* ib1   = (const float*)d_in[4];
    const float* iw2   = (const float*)d_in[5];
    const float* ib2   = (const float*)d_in[6];
    const float* rw1   = (const float*)d_in[7];
    const float* rb1   = (const float*)d_in[8];
    const float* rw2   = (const float*)d_in[9];
    const float* rb2   = (const float*)d_in[10];
    float* out = (float*)d_out;

    char* ws = (char*)d_ws;
    float* qhp  = (float*)(ws);                          // 8*4096*128*4 = 16.78 MB
    float* segp = (float*)(ws + 17u * 1024 * 1024);      // 16*100*256*4 = 1.64 MB
    float* shwT = (float*)(ws + 19u * 1024 * 1024);      // 128*100*4 = 51.2 KB
    float* impA = (float*)(ws + 19u * 1024 * 1024 + 64 * 1024);
    float* cA   = (float*)(ws + 19u * 1024 * 1024 + 65 * 1024);
    float* wvO  = (float*)(ws + 20u * 1024 * 1024);      // 4096*16*4 = 256 KB
    int*   idxO = (int*)  (ws + 20u * 1024 * 1024 + 256 * 1024);

    hipLaunchKernelGGL(k_seg_gemm, dim3(25, 16), dim3(256), 0, stream, seg, iw1, rw1, segp);
    hipLaunchKernelGGL(k_seg_red, dim3(NSEG), dim3(256), 0, stream,
                       segp, pos, ib1, iw2, ib2, rb1, shwT, impA, cA);
    hipLaunchKernelGGL(k_qh, dim3(32, 8), dim3(256), 0, stream, query, rw1, qhp);
    hipLaunchKernelGGL(k_score, dim3(BROWS), dim3(256), 0, stream,
                       qhp, shwT, rw2, rb2, impA, cA, wvO, idxO);
    hipLaunchKernelGGL(k_out, dim3(BROWS), dim3(256), 0, stream,
                       query, seg, wvO, idxO, out);
}